// Round 17
// baseline (363.135 us; speedup 1.0000x reference)
//
#include <hip/hip_runtime.h>
#include <math.h>

#define HIDDEN 4096
#define QKV_N 6144      // (32 + 2*8) * 128
#define T_LEN 2048
#define HD 128
#define N_HEADS 32
#define N_KV 8
#define SCALE 0.08838834764831845f  // 128^-0.5

typedef unsigned short u16;
typedef unsigned int u32;
typedef __attribute__((ext_vector_type(8))) short bf16x8;
typedef __attribute__((ext_vector_type(4))) float f32x4;

// fp32 -> bf16 round-to-nearest-even
__device__ __forceinline__ u16 f2b(float x) {
  u32 u = __builtin_bit_cast(u32, x);
  u += 0x7fffu + ((u >> 16) & 1u);
  return (u16)(u >> 16);
}

typedef const __attribute__((address_space(1))) void* gas_ptr;
typedef __attribute__((address_space(3))) void* las_ptr;
__device__ __forceinline__ void gll16(const void* g, void* l) {
  __builtin_amdgcn_global_load_lds((gas_ptr)g, (las_ptr)l, 16, 0, 0);
}

// ---------------------------------------------------------------------------
// elementwise fp32 -> bf16 cast (4 elems/thread)
// ---------------------------------------------------------------------------
__global__ __launch_bounds__(256) void cast_bf16_kernel(
    const float* __restrict__ in, u16* __restrict__ out) {
  const size_t i = ((size_t)blockIdx.x * 256 + threadIdx.x) * 4;
  f32x4 v = *(const f32x4*)(in + i);
  ushort4 o;
  o.x = f2b(v[0]); o.y = f2b(v[1]); o.z = f2b(v[2]); o.w = f2b(v[3]);
  *(ushort4*)(out + i) = o;
}

// ---------------------------------------------------------------------------
// W [K][N] fp32 -> WT [N][K] bf16 (32x32 LDS tile transpose) — w_qkv only;
// w_o's transpose is absorbed into the attn launch.
// ---------------------------------------------------------------------------
__global__ __launch_bounds__(256) void transpose_cast_kernel(
    const float* __restrict__ W, u16* __restrict__ WT, int K, int N) {
  __shared__ float t[32][33];
  const int n0 = blockIdx.x * 32, k0 = blockIdx.y * 32;
  const int c = threadIdx.x & 31;
  const int r0 = threadIdx.x >> 5;
#pragma unroll
  for (int j = 0; j < 4; ++j) {
    const int r = r0 + 8 * j;
    t[c][r] = W[(size_t)(k0 + r) * N + n0 + c];
  }
  __syncthreads();
#pragma unroll
  for (int j = 0; j < 4; ++j) {
    const int n = r0 + 8 * j;
    WT[(size_t)(n0 + n) * K + k0 + c] = f2b(t[n][c]);
  }
}

// ---------------------------------------------------------------------------
// 8-phase BMxBN bf16 MFMA GEMM (r7 schedule — best measured of 7 variants).
// FUSE=true (QKV call, BM=256,BN=256, grid 24x8): the epilogue applies
// RMSNorm + RoPE + bf16 pack IN-REGISTER and writes Qp/Kp directly
// (Q/K blocks nb<20); V blocks (nb>=20) write compact fp32 Vf32 [t][1024].
// Geometry: 256 cols = 2 heads; head = wave-pair (wc, wc^1); per-row ss =
// in-lane sum over fn + 4 shfl_xor over m + 4KB LDS wave-pair combine;
// RoPE (d,d+32) pairs are IN-LANE (fn <-> fn+2) for the even (wc&1==0)
// wave. sincos computed per-lane (~64 ops, amortized over 300K-cyc kernel).
// vmcnt ledger: vmcnt(ALOADS+BLOADS). Octet swizzle o ^= (r>>1)&3 on
// stage-source AND ds_read -> 0 bank conflicts. No XCD swizzle.
// ---------------------------------------------------------------------------
template <int BM, int BN, bool FUSE>
__global__ __launch_bounds__(512, 2) void gemm256_kernel(
    const u16* __restrict__ A, const u16* __restrict__ BT,
    float* __restrict__ C, int M, int N, int K,
    const int* __restrict__ positions, const float* __restrict__ qw,
    const float* __restrict__ kw, u16* __restrict__ Qp, u16* __restrict__ Kp) {
  constexpr int WCOLS = BN / 4;
  constexpr int NF = WCOLS / 16;
  constexpr int NF2 = NF / 2;
  constexpr int MF = BM / 32;
  constexpr int ALOADS = BM / 128;
  constexpr int BLOADS = BN / 128;
  constexpr int VMN = ALOADS + BLOADS;
  __shared__ __align__(16) u16 As[2][2][BM * 32];
  __shared__ __align__(16) u16 Bs[2][2][BN * 32];

  const int tid = threadIdx.x;
  const int w = tid >> 6, l = tid & 63;
  const int wr = w >> 2, wc = w & 3;
  const int m = l & 15, g = l >> 4;
  const int bm = blockIdx.y * BM, bn = blockIdx.x * BN;
  const int NT = K >> 6;

  size_t gA[2]; int sA[2];
  size_t gB[2]; int sB[2];
#pragma unroll
  for (int i = 0; i < ALOADS; ++i) {
    const int s = i * 512 + tid;
    const int r = s >> 2, o = s & 3;
    sA[i] = s * 8;
    gA[i] = (size_t)(bm + r) * K + (o ^ ((r >> 1) & 3)) * 8;
  }
#pragma unroll
  for (int i = 0; i < BLOADS; ++i) {
    const int s = i * 512 + tid;
    const int r = s >> 2, o = s & 3;
    sB[i] = s * 8;
    gB[i] = (size_t)(bn + r) * K + (o ^ ((r >> 1) & 3)) * 8;
  }

  const int foff = m * 32 + ((g ^ ((m >> 1) & 3)) * 8);
  const int abase = wr * (BM / 2) * 32;
  const int bbase = wc * WCOLS * 32;

#define STAGE_A(tile, kh)                                                      \
  {                                                                            \
    const size_t kofs = (size_t)(tile) * 64 + (kh) * 32;                       \
    u16* dst = &As[(tile) & 1][kh][0];                                         \
    gll16(A + gA[0] + kofs, dst + sA[0]);                                      \
    if constexpr (ALOADS > 1) gll16(A + gA[1] + kofs, dst + sA[1]);            \
  }
#define STAGE_B(tile, kh)                                                      \
  {                                                                            \
    const size_t kofs = (size_t)(tile) * 64 + (kh) * 32;                       \
    u16* dst = &Bs[(tile) & 1][kh][0];                                         \
    gll16(BT + gB[0] + kofs, dst + sB[0]);                                     \
    if constexpr (BLOADS > 1) gll16(BT + gB[1] + kofs, dst + sB[1]);           \
  }
#define VM_COUNTED()                                                           \
  {                                                                            \
    if constexpr (VMN == 4)                                                    \
      asm volatile("s_waitcnt vmcnt(4)" ::: "memory");                         \
    else                                                                       \
      asm volatile("s_waitcnt vmcnt(3)" ::: "memory");                         \
  }
#define PHASE(j, b, DO_STAGE, tn, VM)                                          \
  {                                                                            \
    constexpr int qn = (j) & 1, kh = (j) >> 1;                                 \
    if constexpr (qn == 0) {                                                   \
      _Pragma("unroll") for (int fm = 0; fm < MF; ++fm)                        \
          af[fm] = *(const bf16x8*)(&As[b][kh][abase + fm * 512 + foff]);      \
    }                                                                          \
    bf16x8 bf[NF2];                                                            \
    _Pragma("unroll") for (int fn = 0; fn < NF2; ++fn)                         \
        bf[fn] =                                                               \
        *(const bf16x8*)(&Bs[b][kh][bbase + (qn * NF2 + fn) * 512 + foff]);    \
    if constexpr (DO_STAGE) {                                                  \
      if constexpr ((j) == 0) STAGE_A(tn, 0);                                  \
      if constexpr ((j) == 1) STAGE_B(tn, 0);                                  \
      if constexpr ((j) == 2) STAGE_A(tn, 1);                                  \
      if constexpr ((j) == 3) STAGE_B(tn, 1);                                  \
    }                                                                          \
    asm volatile("" ::: "memory");                                             \
    __builtin_amdgcn_s_barrier();                                              \
    asm volatile("" ::: "memory");                                             \
    __builtin_amdgcn_s_setprio(1);                                             \
    _Pragma("unroll") for (int fm = 0; fm < MF; ++fm)                          \
        _Pragma("unroll") for (int fn = 0; fn < NF2; ++fn)                     \
        acc[fm][qn * NF2 + fn] = __builtin_amdgcn_mfma_f32_16x16x32_bf16(      \
            af[fm], bf[fn], acc[fm][qn * NF2 + fn], 0, 0, 0);                  \
    __builtin_amdgcn_s_setprio(0);                                             \
    asm volatile("" ::: "memory");                                             \
    if constexpr (((j) & 1) && (VM) == 0)                                      \
      asm volatile("s_waitcnt vmcnt(0)" ::: "memory");                         \
    if constexpr (((j) & 1) && (VM) == 1) VM_COUNTED();                        \
    __builtin_amdgcn_s_barrier();                                              \
    asm volatile("" ::: "memory");                                             \
  }

  f32x4 acc[MF][NF];
#pragma unroll
  for (int i = 0; i < MF; ++i)
#pragma unroll
    for (int j = 0; j < NF; ++j) acc[i][j] = (f32x4){0.f, 0.f, 0.f, 0.f};

  STAGE_A(0, 0); STAGE_B(0, 0); STAGE_A(0, 1); STAGE_B(0, 1);
  VM_COUNTED();
  __builtin_amdgcn_s_barrier();
  asm volatile("" ::: "memory");

  bf16x8 af[MF];
  for (int t = 0; t < NT - 1; ++t) {
    const int b = t & 1, tn = t + 1;
    PHASE(0, b, true, tn, 1);
    PHASE(1, b, true, tn, 1);
    PHASE(2, b, true, tn, 1);
    PHASE(3, b, true, tn, 1);
  }
  {
    const int b = (NT - 1) & 1;
    PHASE(0, b, false, 0, 2);
    PHASE(1, b, false, 0, 0);
    PHASE(2, b, false, 0, 2);
    PHASE(3, b, false, 0, 2);
  }
#undef PHASE
#undef VM_COUNTED
#undef STAGE_B
#undef STAGE_A

  if constexpr (FUSE) {
    // ===== fused QKV epilogue =====
    const int nb = blockIdx.x;  // 0..23: nb<16 Q, 16..19 K, 20..23 V
    if (nb < 20) {
      __syncthreads();  // tail phase had no barrier; LDS now reusable
      float* ssbuf = (float*)&As[0][0][0];  // 8 waves x 128 rows = 4KB
      const bool isq = nb < 16;
      const int dbase = (w & 1) * 64;       // head-half owned by this wave
      const int hsel = (w >> 1) & 1;        // which of the block's 2 heads
      const float* wvec = isq ? qw : kw;
      float wt[4];
#pragma unroll
      for (int fn = 0; fn < 4; ++fn) wt[fn] = wvec[dbase + fn * 16 + m];

      // pass 1: per-row sum of squares over this wave's 64 cols
#pragma unroll
      for (int fm = 0; fm < MF; ++fm)
#pragma unroll
        for (int r = 0; r < 4; ++r) {
          float ss = 0.f;
#pragma unroll
          for (int fn = 0; fn < 4; ++fn) {
            const float v = acc[fm][fn][r];
            ss += v * v;
          }
          ss += __shfl_xor(ss, 1);
          ss += __shfl_xor(ss, 2);
          ss += __shfl_xor(ss, 4);
          ss += __shfl_xor(ss, 8);
          if (m == 0) ssbuf[w * 128 + fm * 16 + g * 4 + r] = ss;
        }
      __syncthreads();

      const float invf0 = powf(1.0e6f, -(float)m * (1.0f / 32.0f));
      const float invf1 = powf(1.0e6f, -(float)(16 + m) * (1.0f / 32.0f));
      u16* outp = isq ? Qp + (size_t)(2 * nb + hsel) * T_LEN * HD
                      : Kp + (size_t)(2 * (nb - 16) + hsel) * T_LEN * HD;
      const float oscale = isq ? SCALE : 1.0f;

#pragma unroll
      for (int fm = 0; fm < MF; ++fm) {
#pragma unroll
        for (int r = 0; r < 4; ++r) {
          const int lrow = fm * 16 + g * 4 + r;
          const int t = bm + wr * 128 + lrow;
          const float tot = ssbuf[w * 128 + lrow] + ssbuf[(w ^ 1) * 128 + lrow];
          const float inv = rsqrtf(tot * (1.0f / 128.0f) + 1e-6f);
          float xn[4];
#pragma unroll
          for (int fn = 0; fn < 4; ++fn) xn[fn] = acc[fm][fn][r] * inv * wt[fn];
          float o0, o1, o2, o3;
          if ((w & 1) == 0) {  // rotated half (d < 64); pairs in-lane
            const float p = (float)positions[t];
            const float fr0 = p * invf0, fr1 = p * invf1;
            const float c0 = cosf(fr0), s0 = sinf(fr0);
            const float c1 = cosf(fr1), s1 = sinf(fr1);
            o0 = xn[0] * c0 - xn[2] * s0;
            o1 = xn[1] * c1 - xn[3] * s1;
            o2 = xn[2] * c0 + xn[0] * s0;
            o3 = xn[3] * c1 + xn[1] * s1;
          } else {  // pass-through half (d >= 64)
            o0 = xn[0]; o1 = xn[1]; o2 = xn[2]; o3 = xn[3];
          }
          u16* op = outp + (size_t)t * HD + dbase + m;
          op[0] = f2b(o0 * oscale);
          op[16] = f2b(o1 * oscale);
          op[32] = f2b(o2 * oscale);
          op[48] = f2b(o3 * oscale);
        }
      }
    } else {
      // V blocks: compact fp32 [t][1024] (read by vtrans)
      const int vb = (nb - 20) * 256;
#pragma unroll
      for (int fm = 0; fm < MF; ++fm) {
        const int row = bm + wr * 128 + fm * 16 + g * 4;
#pragma unroll
        for (int fn = 0; fn < NF; ++fn) {
          const int col = vb + wc * WCOLS + fn * 16 + m;
          float* cp = C + (size_t)row * 1024 + col;
#pragma unroll
          for (int r = 0; r < 4; ++r) cp[(size_t)r * 1024] = acc[fm][fn][r];
        }
      }
    }
  } else {
    // standard C write (O-proj)
#pragma unroll
    for (int fm = 0; fm < MF; ++fm) {
      const int row = bm + wr * (BM / 2) + fm * 16 + g * 4;
#pragma unroll
      for (int fn = 0; fn < NF; ++fn) {
        const int col = bn + wc * WCOLS + fn * 16 + m;
        float* cp = C + (size_t)row * N + col;
#pragma unroll
        for (int r = 0; r < 4; ++r) cp[(size_t)r * N] = acc[fm][fn][r];
      }
    }
  }
}

// ---------------------------------------------------------------------------
// V transpose+cast: Vf32 [t][kvh*128+d] (stride 1024) -> Vtp[kvh][d][t] bf16.
// ---------------------------------------------------------------------------
__global__ __launch_bounds__(256) void vtrans_kernel(
    const float* __restrict__ Vf32, u16* __restrict__ Vtp) {
  __shared__ float tile[32][132];
  const int t0 = blockIdx.x * 32;
  const int kvh = blockIdx.y;
  const int tv = threadIdx.x >> 3;          // 0..31
  const int c0 = (threadIdx.x & 7) * 16;    // 0..112
  const float* src = Vf32 + (size_t)(t0 + tv) * 1024 + kvh * HD + c0;
#pragma unroll
  for (int u = 0; u < 4; ++u)
    *(f32x4*)&tile[tv][c0 + 4 * u] = *(const f32x4*)(src + 4 * u);
  __syncthreads();
  const int dd = threadIdx.x >> 1;   // 0..127
  const int half = threadIdx.x & 1;  // 0,1
  u16 buf[16];
#pragma unroll
  for (int p = 0; p < 16; ++p) buf[p] = f2b(tile[half * 16 + p][dd]);
  u16* dst = Vtp + ((size_t)kvh * HD + dd) * T_LEN + t0 + half * 16;
  *(uint4*)dst = *(uint4*)&buf[0];
  *(uint4*)(dst + 8) = *(uint4*)&buf[8];
}

// ---------------------------------------------------------------------------
// MFMA causal GQA flash attention (attn4) + absorbed w_o transpose.
// grid (24, 32): bx<16 = attn (balanced pairing, 2 blocks/CU); bx>=16 =
// 256 transpose blocks x 64 32x32 tiles of w_o. 256 thr, 52KB -> 3/CU.
// ---------------------------------------------------------------------------
__global__ __launch_bounds__(256, 3) void attn4_kernel(
    const u16* __restrict__ Qp, const u16* __restrict__ Kp,
    const u16* __restrict__ Vtp, u16* __restrict__ outB,
    const float* __restrict__ w_o, u16* __restrict__ woT) {
  __shared__ __align__(16) u16 Qs[64 * 128];
  __shared__ __align__(16) u16 Ks[2 * 32 * 128];
  __shared__ __align__(16) u16 Vts[2 * 128 * 32];
  __shared__ __align__(16) u16 Plds[4 * 16 * 32];

  const int bx = blockIdx.x;  // 0..23
  const int h = blockIdx.y;
  const int tid = threadIdx.x;

  if (bx >= 16) {  // ---- w_o transpose role (256 blocks x 64 tiles) ----
    float(*tf)[33] = (float(*)[33])Qs;  // 4.2KB alias into Qs
    const int e = (bx - 16) + 8 * h;    // 0..255
    const int c = tid & 31, rr = tid >> 5;
    for (int tt = e * 64; tt < e * 64 + 64; ++tt) {
      const int n0 = (tt & 127) * 32, k0 = (tt >> 7) * 32;
#pragma unroll
      for (int j = 0; j < 4; ++j) {
        const int r = rr + 8 * j;
        tf[c][r] = w_o[(size_t)(k0 + r) * HIDDEN + n0 + c];
      }
      __syncthreads();
#pragma unroll
      for (int j = 0; j < 4; ++j) {
        const int n = rr + 8 * j;
        woT[(size_t)(n0 + n) * HIDDEN + k0 + c] = f2b(tf[n][c]);
      }
      __syncthreads();
    }
    return;
  }

  const int kvh = h >> 2;
  const int w = tid >> 6, l = tid & 63;
  const int g = l >> 4, m = l & 15;

  const u16* kbase = Kp + (size_t)kvh * T_LEN * HD;
  const u16* vbase = Vtp + (size_t)kvh * HD * T_LEN;
  u16* pl = Plds + w * 512;  // per-wave P bounce [16 m][32 kv]

#define STAGE_KV(jt, b)                                                        \
  {                                                                            \
    _Pragma("unroll") for (int p = 0; p < 2; ++p) {                            \
      const int krow = p * 16 + w * 4 + (l >> 4);                              \
      const int kg = (l & 15) ^ (krow & 7);                                    \
      gll16(kbase + (size_t)((jt) * 32 + krow) * 128 + kg * 8,                 \
            Ks + (b) * 4096 + p * 2048 + w * 512 + l * 8);                     \
      const int dv = p * 64 + w * 16 + (l >> 2);                               \
      const int vg = (l & 3) ^ ((dv >> 1) & 3);                                \
      gll16(vbase + (size_t)dv * T_LEN + (jt) * 32 + vg * 8,                   \
            Vts + (b) * 4096 + p * 2048 + w * 512 + l * 8);                    \
    }                                                                          \
  }

  for (int job = 0; job < 2; ++job) {
    const int qb = job ? bx : 31 - bx;  // big first (warms KV L2 for small)
    const int t0 = qb * 64;
    const int NT = 2 * (qb + 1);

    // ---- stage Q tile (swizzle: 16B granule ^ (row&7)) ----
    {
      const u16* qbase = Qp + ((size_t)h * T_LEN + t0) * HD;
#pragma unroll
      for (int p = 0; p < 4; ++p) {
        const int row = p * 16 + w * 4 + (l >> 4);
        const int gr = (l & 15) ^ (row & 7);
        gll16(qbase + row * 128 + gr * 8, Qs + p * 2048 + w * 512 + l * 8);
      }
    }
    STAGE_KV(0, 0);
    __syncthreads();

    // ---- hoist Q B-fragments ----
    bf16x8 qf[4];
    {
      const u16* qr = Qs + (w * 16 + m) * 128;
#pragma unroll
      for (int kk = 0; kk < 4; ++kk)
        qf[kk] = *(const bf16x8*)(qr + (((kk * 4 + g) ^ (m & 7)) * 8));
    }

    f32x4 o[8];
#pragma unroll
    for (int n = 0; n < 8; ++n) o[n] = (f32x4){0.f, 0.f, 0.f, 0.f};
    float mrun = -1e30f, lrun = 0.f;

    for (int jt = 0; jt < NT; ++jt) {
      const int b = jt & 1;
      if (jt + 1 < NT) STAGE_KV(jt + 1, b ^ 1);

      // ---- S^T = K @ Q^T ----
      f32x4 s[2];
      s[0] = (f32x4){0.f, 0.f, 0.f, 0.f};
      s[1] = (f32x4){0.f, 0.f, 0.f, 0.f};
      __builtin_amdgcn_s_setprio(1);
#pragma unroll
      for (int f = 0; f < 2; ++f) {
        const u16* kr = Ks + b * 4096 + (f * 16 + m) * 128;
#pragma unroll
        for (int kk = 0; kk < 4; ++kk) {
          bf16x8 kf = *(const bf16x8*)(kr + (((kk * 4 + g) ^ (m & 7)) * 8));
          s[f] =
              __builtin_amdgcn_mfma_f32_16x16x32_bf16(kf, qf[kk], s[f], 0, 0, 0);
        }
      }
      __builtin_amdgcn_s_setprio(0);

      // ---- causal mask (only last two tiles can clip) ----
      if (jt >= NT - 2) {
        const int qg = t0 + w * 16 + m;
        const int kvb = jt * 32 + g * 4;
#pragma unroll
        for (int f = 0; f < 2; ++f)
#pragma unroll
          for (int r = 0; r < 4; ++r)
            if (kvb + f * 16 + r > qg) s[f][r] = -1e30f;
      }

      // ---- online softmax with defer-max (T13, THR=8) ----
      float pm = fmaxf(fmaxf(fmaxf(s[0][0], s[0][1]), fmaxf(s[0][2], s[0][3])),
                       fmaxf(fmaxf(s[1][0], s[1][1]), fmaxf(s[1][2], s[1][3])));
      pm = fmaxf(pm, __shfl_xor(pm, 16));
      pm = fmaxf(pm, __shfl_xor(pm, 32));
      if (!__all(pm <= mrun + 8.f)) {
        const float mn = fmaxf(mrun, pm);
        const float sc = __expf(mrun - mn);
        mrun = mn;
        lrun *= sc;
        f32x4 scr;
#pragma unroll
        for (int r = 0; r < 4; ++r) scr[r] = __shfl(sc, g * 4 + r);
#pragma unroll
        for (int n = 0; n < 8; ++n) o[n] *= scr;
      }
      float ps = 0.f;
#pragma unroll
      for (int f = 0; f < 2; ++f)
#pragma unroll
        for (int r = 0; r < 4; ++r) {
          s[f][r] = __expf(s[f][r] - mrun);
          ps += s[f][r];
        }
      ps += __shfl_xor(ps, 16);
      ps += __shfl_xor(ps, 32);
      lrun += ps;

      // ---- P -> LDS bounce (wave-private) ----
      {
        const u32 a0 = (u32)f2b(s[0][0]) | ((u32)f2b(s[0][1]) << 16);
        const u32 a1 = (u32)f2b(s[0][2]) | ((u32)f2b(s[0][3]) << 16);
        const u32 b0 = (u32)f2b(s[1][0]) | ((u32)f2b(s[1][1]) << 16);
        const u32 b1 = (u32)f2b(s[1][2]) | ((u32)f2b(s[1][3]) << 16);
        *(uint2*)(pl + m * 32 + ((g ^ (m >> 1)) * 4)) = make_uint2(a0, a1);
        *(uint2*)(pl + m * 32 + (((g + 4) ^ (m >> 1)) * 4)) = make_uint2(b0, b1);
      }

      // ---- read P A-fragment ----
      bf16x8 pa;
      {
        const uint2 lo =
            *(const uint2*)(pl + m * 32 + (((2 * g) ^ (m >> 1)) * 4));
        const uint2 hi =
            *(const uint2*)(pl + m * 32 + (((2 * g + 1) ^ (m >> 1)) * 4));
        union { u32 u[4]; bf16x8 v; } pu;
        pu.u[0] = lo.x; pu.u[1] = lo.y; pu.u[2] = hi.x; pu.u[3] = hi.y;
        pa = pu.v;
      }

      // ---- PV ----
      __builtin_amdgcn_s_setprio(1);
#pragma unroll
      for (int n = 0; n < 8; ++n) {
        const int dd = n * 16 + m;
        bf16x8 vf = *(const bf16x8*)(Vts + b * 4096 + dd * 32 +
                                     ((g ^ ((dd >> 1) & 3)) * 8));
        o[n] = __builtin_amdgcn_mfma_f32_16x16x32_bf16(pa, vf, o[n], 0, 0, 0);
      }
      __builtin_amdgcn_s_setprio(0);
      __syncthreads();
    }

    // ---- epilogue: normalize rows, write bf16 [t][h*128+d] ----
    float li[4];
#pragma unroll
    for (int r = 0; r < 4; ++r) li[r] = 1.f / __shfl(lrun, g * 4 + r);
    u16* ob = outB + (size_t)(t0 + w * 16 + g * 4) * HIDDEN + h * HD + m;
#pragma unroll
    for (int n = 0; n < 8; ++n)
#pragma unroll
      for (int r = 0; r < 4; ++r)
        ob[(size_t)r * HIDDEN + n * 16] = f2b(o[n][r] * li[r]);
  }
#undef STAGE_KV
}

// ---------------------------------------------------------------------------
extern "C" void kernel_launch(void* const* d_in, const int* in_sizes, int n_in,
                              void* d_out, int out_size, void* d_ws,
                              size_t ws_size, hipStream_t stream) {
  const float* hidden = (const float*)d_in[0];
  const int* positions = (const int*)d_in[1];
  const float* w_qkv = (const float*)d_in[2];
  const float* w_o = (const float*)d_in[3];
  const float* q_norm_w = (const float*)d_in[4];
  const float* k_norm_w = (const float*)d_in[5];
  float* out = (float*)d_out;

  // workspace layout (~151 MB). Qp has its OWN buffer (the fused GEMM
  // epilogue writes it while other blocks still read hiddenB).
  u16* hiddenB = (u16*)d_ws;                                // 16.8 MB
  u16* wqkvT = hiddenB + (size_t)T_LEN * HIDDEN;            // 50.3 MB
  u16* woT = wqkvT + (size_t)QKV_N * HIDDEN;                // 33.6 MB
  float* Vf32 = (float*)(woT + (size_t)HIDDEN * HIDDEN);    // 8.4 MB
  u16* attnB = (u16*)(Vf32 + (size_t)T_LEN * 1024);         // 16.8 MB
  u16* Kp = attnB + (size_t)T_LEN * HIDDEN;                 // 4.2 MB
  u16* Vtp = Kp + (size_t)N_KV * T_LEN * HD;                // 4.2 MB
  u16* Qp = Vtp + (size_t)N_KV * HD * T_LEN;                // 16.8 MB

  // prep
  cast_bf16_kernel<<<(T_LEN * HIDDEN) / 1024, 256, 0, stream>>>(hidden, hiddenB);
  transpose_cast_kernel<<<dim3(QKV_N / 32, HIDDEN / 32), 256, 0, stream>>>(
      w_qkv, wqkvT, HIDDEN, QKV_N);

  // 1) QKV GEMM with fused RMSNorm+RoPE+pack epilogue -> Qp, Kp, Vf32
  gemm256_kernel<256, 256, true>
      <<<dim3(QKV_N / 256, T_LEN / 256), 512, 0, stream>>>(
          hiddenB, wqkvT, Vf32, T_LEN, 1024, HIDDEN, positions, q_norm_w,
          k_norm_w, Qp, Kp);
  // 2) V transpose -> Vtp
  vtrans_kernel<<<dim3(T_LEN / 32, N_KV), 256, 0, stream>>>(Vf32, Vtp);
  // 3) attn (bx<16) + absorbed w_o transpose (bx>=16) -> attnB, woT
  attn4_kernel<<<dim3(24, N_HEADS), 256, 0, stream>>>(Qp, Kp, Vtp, attnB, w_o,
                                                      woT);
  // 4) out = attn @ w_o  (8-phase 128x256, grid 16x16 = 256 = full coverage)
  gemm256_kernel<128, 256, false>
      <<<dim3(HIDDEN / 256, T_LEN / 128), 512, 0, stream>>>(
          attnB, woT, out, T_LEN, HIDDEN, HIDDEN, nullptr, nullptr, nullptr,
          nullptr, nullptr);
}